// Round 8
// baseline (511.224 us; speedup 1.0000x reference)
//
#include <hip/hip_runtime.h>
#include <cmath>

// ---------------- problem constants ----------------
#define NLAYERS 100      // hidden layers (scan)
#define DIN     64       // input features
#define WDIM    100      // hidden width
#define NPAD    112      // padded N (7 tiles of 16)
#define NT      7        // n tiles
#define RT      2        // row tiles -> 32 batch rows/wave; W-frags shared across both
#define ROWS    32
#define PSTR    136      // f16 plane row stride (272 B: b128-aligned, pad cols 112..127)
#define PLANE   (16 * PSTR)   // one plane (one row-tile) in halves; 2 planes = 8704 B

typedef _Float16 half8 __attribute__((ext_vector_type(8)));
typedef __fp16   fp16x2 __attribute__((ext_vector_type(2)));
typedef float    f32x4 __attribute__((ext_vector_type(4)));

// ---------------- workspace layout ----------------
#define WSH_LAYER_HALVES (NT * 4 * 64 * 8)               // 14336 halves per hidden layer
#define WSH_HALVES       (NLAYERS * WSH_LAYER_HALVES)    // 1,433,600
#define W0_HALVES        (NT * 2 * 64 * 8)               // 7168 (input layer, K=64)
#define BPAD_FLOATS      ((NLAYERS + 1) * NPAD)          // 11312 (row 0 = b_in acc init)
#define OFF_BPAD_B       ((WSH_HALVES + W0_HALVES) * 2)  // bytes, 16-aligned
#define OFF_WOUT_B       (OFF_BPAD_B + BPAD_FLOATS * 4)  // bytes, 16-aligned
#define TOTAL_PREP       (WSH_HALVES + W0_HALVES + BPAD_FLOATS + NPAD)

// ============================================================
// Prep: shuffle weights into MFMA A-operand order (f16), operand-swapped:
// frag (nt,ks), lane(q,l15), elem j holds W[k=ks*32+q*8+j][n=nt*16+l15].
// Row k==112 of each hidden-layer fragment = layer bias (h col 112 == 1.0).
// ============================================================
__global__ void actor_prep(const float* __restrict__ Win, const float* __restrict__ bin,
                           const float* __restrict__ Ws,  const float* __restrict__ bs,
                           const float* __restrict__ Wout,
                           _Float16* __restrict__ wsh, _Float16* __restrict__ w0sh,
                           float* __restrict__ bpad, float* __restrict__ woutp) {
    int t = blockIdx.x * 256 + threadIdx.x;
    if (t < WSH_HALVES) {                       // hidden-layer weights (+ bias row at k=112)
        int j    = t & 7;
        int lane = (t >> 3) & 63;
        int ks   = (t >> 9) & 3;
        int rest = t >> 11;                     // l*7 + nt
        int nt   = rest % 7;
        int l    = rest / 7;
        int qq = lane >> 4, ll = lane & 15;
        int k = ks * 32 + qq * 8 + j;
        int n = nt * 16 + ll;
        float v = 0.f;
        if (k < WDIM && n < WDIM)       v = Ws[(l * WDIM + k) * WDIM + n];
        else if (k == 112 && n < WDIM)  v = bs[l * WDIM + n];   // bias row
        wsh[t] = (_Float16)v;
        return;
    }
    int t2 = t - WSH_HALVES;
    if (t2 < W0_HALVES) {                       // input layer weights (K=64, bias via acc init)
        int j    = t2 & 7;
        int lane = (t2 >> 3) & 63;
        int ks   = (t2 >> 9) & 1;
        int nt   = t2 >> 10;
        int qq = lane >> 4, ll = lane & 15;
        int k = ks * 32 + qq * 8 + j;
        int n = nt * 16 + ll;
        float v = (k < DIN && n < WDIM) ? Win[k * WDIM + n] : 0.f;
        w0sh[t2] = (_Float16)v;
        return;
    }
    int t3 = t2 - W0_HALVES;
    if (t3 < BPAD_FLOATS) {                     // padded biases: row 0 = b_in
        int l = t3 / NPAD, c = t3 % NPAD;
        float v = 0.f;
        if (c < WDIM) v = (l == 0) ? bin[c] : bs[(l - 1) * WDIM + c];
        bpad[t3] = v;
        return;
    }
    int t4 = t3 - BPAD_FLOATS;
    if (t4 < NPAD) woutp[t4] = (t4 < WDIM) ? Wout[t4] : 0.f;
}

// split fp32 -> hi/lo fp16 (layer-0 input only: keep input fidelity, ~free)
__device__ __forceinline__ void split8(const float* __restrict__ p, half8& hi, half8& lo) {
    f32x4 u0 = *(const f32x4*)p;
    f32x4 u1 = *(const f32x4*)(p + 4);
    float v[8] = {u0[0], u0[1], u0[2], u0[3], u1[0], u1[1], u1[2], u1[3]};
#pragma unroll
    for (int e = 0; e < 8; e += 2) {
        fp16x2 h = __builtin_amdgcn_cvt_pkrtz(v[e], v[e + 1]);
        float r0 = v[e]     - (float)h[0];
        float r1 = v[e + 1] - (float)h[1];
        fp16x2 l = __builtin_amdgcn_cvt_pkrtz(r0, r1);
        hi[e] = (_Float16)h[0]; hi[e + 1] = (_Float16)h[1];
        lo[e] = (_Float16)l[0]; lo[e + 1] = (_Float16)l[1];
    }
}

// ============================================================
// Main: one wave/block, 32 batch rows (2 row-tiles), network fused.
// HI-ONLY activations (f16 RNE): per-layer activation quantization
// 2^-11 rel random-walks over 100 layers ≈ 2.8e-3 rel — below the f16
// weight-rounding floor (4.9e-3). Halves MFMA count AND epilogue VALU
// vs the hi/lo scheme. Operand-swapped mfma(Wfrag, hfrag, acc); one set
// of 28 W-frag loads/layer feeds both row-tiles. Bias rides W row k=112
// against h col 112 == 1.0. Head computed from final fp32 accs in regs.
// No barriers: wave owns its plane. 2048 blocks = 2 waves/SIMD.
// ============================================================
__global__ __launch_bounds__(64, 2)
void actor_main(const float* __restrict__ x,
                const _Float16* __restrict__ wsh,
                const _Float16* __restrict__ w0sh,
                const float* __restrict__ bpad,
                const float* __restrict__ woutp,
                const float* __restrict__ bout,
                float* __restrict__ out) {
    __shared__ _Float16 hp[2 * PLANE];   // [rt] hi planes only
    const int lane = threadIdx.x;
    const int q = lane >> 4, l15 = lane & 15;
    const int rowbase = blockIdx.x * ROWS;

    f32x4 acc[RT][NT];
    half8 wb[2][NT];                 // double-buffered W fragments (A operand), 1 k-step ahead
    const f32x4 zero4 = {0.f, 0.f, 0.f, 0.f};

    // ---- one-time pad init: cols 112..127 zero in both planes, then [.,112]=1.0 ----
    {
        const int pl = lane >> 5, row = (lane >> 1) & 15, cg = lane & 1;
        const half8 z = {0, 0, 0, 0, 0, 0, 0, 0};
        *(half8*)(hp + pl * PLANE + row * PSTR + 112 + cg * 8) = z;
        if (lane < 32) {
            const int rt = lane >> 4, r = lane & 15;
            hp[rt * PLANE + r * PSTR + 112] = (_Float16)1.0f;   // bias multiplier
        }
    }

    // preload input-layer ks=0 W frags; acc init = b_in
#pragma unroll
    for (int nt = 0; nt < NT; ++nt) {
        wb[0][nt] = *(const half8*)(w0sh + ((nt * 2 + 0) * 64 + lane) * 8);
        f32x4 b = *(const f32x4*)(bpad + nt * 16 + q * 4);
        acc[0][nt] = b;
        acc[1][nt] = b;
    }

    // ---------------- layer 0: x @ W_in (K=64), hi+lo split of fp32 x ----------------
#pragma unroll
    for (int ks = 0; ks < 2; ++ks) {
        const int cur = ks & 1, nxt = cur ^ 1;
        if (ks == 0) {
#pragma unroll
            for (int nt = 0; nt < NT; ++nt)
                wb[nxt][nt] = *(const half8*)(w0sh + ((nt * 2 + 1) * 64 + lane) * 8);
        } else {          // prefetch hidden layer 0, ks=0
#pragma unroll
            for (int nt = 0; nt < NT; ++nt)
                wb[nxt][nt] = *(const half8*)(wsh + lane * 8 + nt * 4 * 64 * 8);
        }
#pragma unroll
        for (int rt = 0; rt < RT; ++rt) {
            half8 xhi, xlo;
            split8(x + (rowbase + rt * 16 + l15) * DIN + ks * 32 + q * 8, xhi, xlo);
#pragma unroll
            for (int nt = 0; nt < NT; ++nt) {
                acc[rt][nt] = __builtin_amdgcn_mfma_f32_16x16x32_f16(wb[cur][nt], xhi, acc[rt][nt], 0, 0, 0);
                acc[rt][nt] = __builtin_amdgcn_mfma_f32_16x16x32_f16(wb[cur][nt], xlo, acc[rt][nt], 0, 0, 0);
            }
        }
    }
    // epilogue 0: leaky + RNE f16 + b64 store (pad neurons 100..111 stay exact 0)
#pragma unroll
    for (int rt = 0; rt < RT; ++rt)
#pragma unroll
        for (int nt = 0; nt < NT; ++nt) {
            f32x4 a = acc[rt][nt];
            half8* unused;
            _Float16 h0 = (_Float16)fmaxf(a[0], 0.01f * a[0]);   // RNE casts
            _Float16 h1 = (_Float16)fmaxf(a[1], 0.01f * a[1]);
            _Float16 h2 = (_Float16)fmaxf(a[2], 0.01f * a[2]);
            _Float16 h3 = (_Float16)fmaxf(a[3], 0.01f * a[3]);
            const int idx = l15 * PSTR + nt * 16 + q * 4;
            _Float16* d = hp + rt * PLANE + idx;
            d[0] = h0; d[1] = h1; d[2] = h2; d[3] = h3;   // contiguous -> ds_write_b64
            (void)unused;
        }

    // ---------------- 100 hidden layers ----------------
#pragma unroll 1
    for (int l = 0; l < NLAYERS; ++l) {
        const _Float16* wl = wsh + l * WSH_LAYER_HALVES;
        const _Float16* wlnext = wsh + (l < NLAYERS - 1 ? l + 1 : l) * WSH_LAYER_HALVES;
#pragma unroll
        for (int rt = 0; rt < RT; ++rt)
#pragma unroll
            for (int nt = 0; nt < NT; ++nt) acc[rt][nt] = zero4;   // bias via k=112 row

#pragma unroll
        for (int ks = 0; ks < 4; ++ks) {
            const int cur = ks & 1, nxt = cur ^ 1;
            // prefetch next k-step (or next layer's ks=0) W frags — shared by both row-tiles
            const _Float16* src = (ks < 3) ? (wl + ((ks + 1) * 64 + lane) * 8)
                                           : (wlnext + lane * 8);
#pragma unroll
            for (int nt = 0; nt < NT; ++nt)
                wb[nxt][nt] = *(const half8*)(src + nt * 4 * 64 * 8);

#pragma unroll
            for (int rt = 0; rt < RT; ++rt) {
                // bare b128 read (ks=3 covers bias col 112=1.0 and zero pads)
                half8 bhi = *(const half8*)(hp + rt * PLANE + l15 * PSTR + ks * 32 + q * 8);
#pragma unroll
                for (int nt = 0; nt < NT; ++nt)
                    acc[rt][nt] = __builtin_amdgcn_mfma_f32_16x16x32_f16(wb[cur][nt], bhi, acc[rt][nt], 0, 0, 0);
            }
        }
        // epilogue: leaky + RNE f16 + b64 store (wasted for l=99; head uses regs)
#pragma unroll
        for (int rt = 0; rt < RT; ++rt)
#pragma unroll
            for (int nt = 0; nt < NT; ++nt) {
                f32x4 a = acc[rt][nt];
                _Float16 h0 = (_Float16)fmaxf(a[0], 0.01f * a[0]);
                _Float16 h1 = (_Float16)fmaxf(a[1], 0.01f * a[1]);
                _Float16 h2 = (_Float16)fmaxf(a[2], 0.01f * a[2]);
                _Float16 h3 = (_Float16)fmaxf(a[3], 0.01f * a[3]);
                const int idx = l15 * PSTR + nt * 16 + q * 4;
                _Float16* d = hp + rt * PLANE + idx;
                d[0] = h0; d[1] = h1; d[2] = h2; d[3] = h3;
            }
    }

    // ---------------- head: leaky + dot(W_out) from final fp32 accs ----------------
#pragma unroll
    for (int rt = 0; rt < RT; ++rt) {
        float s = 0.f;
#pragma unroll
        for (int nt = 0; nt < NT; ++nt) {
            f32x4 w4 = *(const f32x4*)(woutp + nt * 16 + q * 4);
#pragma unroll
            for (int r = 0; r < 4; ++r) {
                float a = acc[rt][nt][r];
                float v = fmaxf(a, 0.01f * a);
                s += v * w4[r];
            }
        }
        s += __shfl_xor(s, 16);   // reduce across the 4 q-groups
        s += __shfl_xor(s, 32);
        if (q == 0) {
            float aa = s + bout[0];
            float t = tanhf(aa);
            out[rowbase + rt * 16 + l15] = t * 4.5f + 5.5f;   // (tanh+1)/2*9 + 1
        }
    }
}

extern "C" void kernel_launch(void* const* d_in, const int* in_sizes, int n_in,
                              void* d_out, int out_size, void* d_ws, size_t ws_size,
                              hipStream_t stream) {
    const float* x    = (const float*)d_in[0];
    const float* Win  = (const float*)d_in[1];
    const float* bin  = (const float*)d_in[2];
    const float* Ws   = (const float*)d_in[3];
    const float* bs   = (const float*)d_in[4];
    const float* Wout = (const float*)d_in[5];
    const float* bout = (const float*)d_in[6];
    float* out = (float*)d_out;

    char* ws = (char*)d_ws;
    _Float16* wsh  = (_Float16*)ws;
    _Float16* w0sh = wsh + WSH_HALVES;
    float* bpad  = (float*)(ws + OFF_BPAD_B);
    float* woutp = (float*)(ws + OFF_WOUT_B);

    hipLaunchKernelGGL(actor_prep, dim3((TOTAL_PREP + 255) / 256), dim3(256), 0, stream,
                       Win, bin, Ws, bs, Wout, wsh, w0sh, bpad, woutp);

    const int nrows = in_sizes[0] / DIN;   // 65536
    hipLaunchKernelGGL(actor_main, dim3(nrows / ROWS), dim3(64), 0, stream,
                       x, wsh, w0sh, bpad, woutp, bout, out);
}

// Round 9
// 424.880 us; speedup vs baseline: 1.2032x; 1.2032x over previous
//
#include <hip/hip_runtime.h>
#include <cmath>

// ---------------- problem constants ----------------
#define NLAYERS 100      // hidden layers (scan)
#define DIN     64       // input features
#define WDIM    100      // hidden width
#define NPAD    112      // padded N (7 tiles of 16)
#define NT      7        // n tiles
#define ROWS    16       // batch rows per wave -> 4096 blocks = 4 waves/SIMD (TLP for latency)
#define PSTR    136      // f16 plane row stride (272 B: b128-aligned, pad cols 112..127)
#define PLANE   (16 * PSTR)   // hi plane in halves = 4352 B

typedef _Float16 half8 __attribute__((ext_vector_type(8)));
typedef __fp16   fp16x2 __attribute__((ext_vector_type(2)));
typedef float    f32x4 __attribute__((ext_vector_type(4)));

// ---------------- workspace layout ----------------
#define WSH_LAYER_HALVES (NT * 4 * 64 * 8)               // 14336 halves per hidden layer
#define WSH_HALVES       (NLAYERS * WSH_LAYER_HALVES)    // 1,433,600
#define W0_HALVES        (NT * 2 * 64 * 8)               // 7168 (input layer, K=64)
#define BPAD_FLOATS      ((NLAYERS + 1) * NPAD)          // 11312 (row 0 = b_in acc init)
#define OFF_BPAD_B       ((WSH_HALVES + W0_HALVES) * 2)  // bytes, 16-aligned
#define OFF_WOUT_B       (OFF_BPAD_B + BPAD_FLOATS * 4)  // bytes, 16-aligned
#define TOTAL_PREP       (WSH_HALVES + W0_HALVES + BPAD_FLOATS + NPAD)

// ============================================================
// Prep: shuffle weights into MFMA A-operand order (f16), operand-swapped:
// frag (nt,ks), lane(q,l15), elem j holds W[k=ks*32+q*8+j][n=nt*16+l15].
// Row k==112 of each hidden-layer fragment = layer bias (h col 112 == 1.0).
// ============================================================
__global__ void actor_prep(const float* __restrict__ Win, const float* __restrict__ bin,
                           const float* __restrict__ Ws,  const float* __restrict__ bs,
                           const float* __restrict__ Wout,
                           _Float16* __restrict__ wsh, _Float16* __restrict__ w0sh,
                           float* __restrict__ bpad, float* __restrict__ woutp) {
    int t = blockIdx.x * 256 + threadIdx.x;
    if (t < WSH_HALVES) {                       // hidden-layer weights (+ bias row at k=112)
        int j    = t & 7;
        int lane = (t >> 3) & 63;
        int ks   = (t >> 9) & 3;
        int rest = t >> 11;                     // l*7 + nt
        int nt   = rest % 7;
        int l    = rest / 7;
        int qq = lane >> 4, ll = lane & 15;
        int k = ks * 32 + qq * 8 + j;
        int n = nt * 16 + ll;
        float v = 0.f;
        if (k < WDIM && n < WDIM)       v = Ws[(l * WDIM + k) * WDIM + n];
        else if (k == 112 && n < WDIM)  v = bs[l * WDIM + n];   // bias row
        wsh[t] = (_Float16)v;
        return;
    }
    int t2 = t - WSH_HALVES;
    if (t2 < W0_HALVES) {                       // input layer weights (K=64, bias via acc init)
        int j    = t2 & 7;
        int lane = (t2 >> 3) & 63;
        int ks   = (t2 >> 9) & 1;
        int nt   = t2 >> 10;
        int qq = lane >> 4, ll = lane & 15;
        int k = ks * 32 + qq * 8 + j;
        int n = nt * 16 + ll;
        float v = (k < DIN && n < WDIM) ? Win[k * WDIM + n] : 0.f;
        w0sh[t2] = (_Float16)v;
        return;
    }
    int t3 = t2 - W0_HALVES;
    if (t3 < BPAD_FLOATS) {                     // padded biases: row 0 = b_in
        int l = t3 / NPAD, c = t3 % NPAD;
        float v = 0.f;
        if (c < WDIM) v = (l == 0) ? bin[c] : bs[(l - 1) * WDIM + c];
        bpad[t3] = v;
        return;
    }
    int t4 = t3 - BPAD_FLOATS;
    if (t4 < NPAD) woutp[t4] = (t4 < WDIM) ? Wout[t4] : 0.f;
}

// split fp32 -> hi/lo fp16 (layer-0 input only: keep input fidelity, ~free)
__device__ __forceinline__ void split8(const float* __restrict__ p, half8& hi, half8& lo) {
    f32x4 u0 = *(const f32x4*)p;
    f32x4 u1 = *(const f32x4*)(p + 4);
    float v[8] = {u0[0], u0[1], u0[2], u0[3], u1[0], u1[1], u1[2], u1[3]};
#pragma unroll
    for (int e = 0; e < 8; e += 2) {
        fp16x2 h = __builtin_amdgcn_cvt_pkrtz(v[e], v[e + 1]);
        float r0 = v[e]     - (float)h[0];
        float r1 = v[e + 1] - (float)h[1];
        fp16x2 l = __builtin_amdgcn_cvt_pkrtz(r0, r1);
        hi[e] = (_Float16)h[0]; hi[e + 1] = (_Float16)h[1];
        lo[e] = (_Float16)l[0]; lo[e + 1] = (_Float16)l[1];
    }
}

// ============================================================
// Main: one wave/block, 16 batch rows, network fused.
// HI-ONLY activations (f16 RNE; verified absmax 0.094 < 0.109 at r8).
// ROWS=16 -> 4096 blocks = 4 waves/SIMD: the r8 diagnostic showed the
// kernel is latency-bound (~10.5K cyc/layer fixed, all pipes <25%);
// doubled TLP fills the latency holes. Weight stream (28 KB/layer) is
// L1-resident across the in-phase waves of a CU. Operand-swapped
// mfma(Wfrag, hfrag, acc); bias rides W row k=112 vs h col 112 == 1.0.
// Head computed from final fp32 accs in regs. No barriers.
// ============================================================
__global__ __launch_bounds__(64, 4)
void actor_main(const float* __restrict__ x,
                const _Float16* __restrict__ wsh,
                const _Float16* __restrict__ w0sh,
                const float* __restrict__ bpad,
                const float* __restrict__ woutp,
                const float* __restrict__ bout,
                float* __restrict__ out) {
    __shared__ _Float16 hp[PLANE];   // hi plane only
    const int lane = threadIdx.x;
    const int q = lane >> 4, l15 = lane & 15;
    const int rowbase = blockIdx.x * ROWS;

    f32x4 acc[NT];
    half8 wb[2][NT];                 // double-buffered W fragments (A operand), 1 k-step ahead
    const f32x4 zero4 = {0.f, 0.f, 0.f, 0.f};

    // ---- one-time pad init: cols 112..127 zero, then [.,112]=1.0 ----
    {
        const int row = lane >> 2, cg = lane & 3;      // 16 rows x 4 half4-groups
        *(ulong1*)0; // (no-op placeholder removed by compiler)  
    }
    {
        const int row = lane & 15;
        if (lane < 16) {
            const half8 z = {0, 0, 0, 0, 0, 0, 0, 0};
            *(half8*)(hp + row * PSTR + 112) = z;
            *(half8*)(hp + row * PSTR + 120) = z;
            hp[row * PSTR + 112] = (_Float16)1.0f;     // bias multiplier
        }
    }

    // preload input-layer ks=0 W frags; acc init = b_in
#pragma unroll
    for (int nt = 0; nt < NT; ++nt) {
        wb[0][nt] = *(const half8*)(w0sh + ((nt * 2 + 0) * 64 + lane) * 8);
        acc[nt] = *(const f32x4*)(bpad + nt * 16 + q * 4);
    }

    // ---------------- layer 0: x @ W_in (K=64), hi+lo split of fp32 x ----------------
#pragma unroll
    for (int ks = 0; ks < 2; ++ks) {
        const int cur = ks & 1, nxt = cur ^ 1;
        if (ks == 0) {
#pragma unroll
            for (int nt = 0; nt < NT; ++nt)
                wb[nxt][nt] = *(const half8*)(w0sh + ((nt * 2 + 1) * 64 + lane) * 8);
        } else {          // prefetch hidden layer 0, ks=0
#pragma unroll
            for (int nt = 0; nt < NT; ++nt)
                wb[nxt][nt] = *(const half8*)(wsh + lane * 8 + nt * 4 * 64 * 8);
        }
        half8 xhi, xlo;
        split8(x + (rowbase + l15) * DIN + ks * 32 + q * 8, xhi, xlo);
#pragma unroll
        for (int nt = 0; nt < NT; ++nt) {
            acc[nt] = __builtin_amdgcn_mfma_f32_16x16x32_f16(wb[cur][nt], xhi, acc[nt], 0, 0, 0);
            acc[nt] = __builtin_amdgcn_mfma_f32_16x16x32_f16(wb[cur][nt], xlo, acc[nt], 0, 0, 0);
        }
    }
    // epilogue 0: leaky + RNE f16 + b64 store (pad neurons 100..111 stay exact 0)
#pragma unroll
    for (int nt = 0; nt < NT; ++nt) {
        f32x4 a = acc[nt];
        _Float16 h0 = (_Float16)fmaxf(a[0], 0.01f * a[0]);
        _Float16 h1 = (_Float16)fmaxf(a[1], 0.01f * a[1]);
        _Float16 h2 = (_Float16)fmaxf(a[2], 0.01f * a[2]);
        _Float16 h3 = (_Float16)fmaxf(a[3], 0.01f * a[3]);
        _Float16* d = hp + l15 * PSTR + nt * 16 + q * 4;
        d[0] = h0; d[1] = h1; d[2] = h2; d[3] = h3;    // contiguous -> ds_write_b64
    }

    // ---------------- 100 hidden layers ----------------
#pragma unroll 1
    for (int l = 0; l < NLAYERS; ++l) {
        const _Float16* wl = wsh + l * WSH_LAYER_HALVES;
        const _Float16* wlnext = wsh + (l < NLAYERS - 1 ? l + 1 : l) * WSH_LAYER_HALVES;
#pragma unroll
        for (int nt = 0; nt < NT; ++nt) acc[nt] = zero4;   // bias via k=112 row

#pragma unroll
        for (int ks = 0; ks < 4; ++ks) {
            const int cur = ks & 1, nxt = cur ^ 1;
            // prefetch next k-step (or next layer's ks=0) W frags
            const _Float16* src = (ks < 3) ? (wl + ((ks + 1) * 64 + lane) * 8)
                                           : (wlnext + lane * 8);
#pragma unroll
            for (int nt = 0; nt < NT; ++nt)
                wb[nxt][nt] = *(const half8*)(src + nt * 4 * 64 * 8);

            // bare b128 read (ks=3 covers bias col 112=1.0 and zero pads)
            half8 bhi = *(const half8*)(hp + l15 * PSTR + ks * 32 + q * 8);
#pragma unroll
            for (int nt = 0; nt < NT; ++nt)
                acc[nt] = __builtin_amdgcn_mfma_f32_16x16x32_f16(wb[cur][nt], bhi, acc[nt], 0, 0, 0);
        }
        // epilogue: leaky + RNE f16 + b64 store (l=99's store is dead; head uses regs)
#pragma unroll
        for (int nt = 0; nt < NT; ++nt) {
            f32x4 a = acc[nt];
            _Float16 h0 = (_Float16)fmaxf(a[0], 0.01f * a[0]);
            _Float16 h1 = (_Float16)fmaxf(a[1], 0.01f * a[1]);
            _Float16 h2 = (_Float16)fmaxf(a[2], 0.01f * a[2]);
            _Float16 h3 = (_Float16)fmaxf(a[3], 0.01f * a[3]);
            _Float16* d = hp + l15 * PSTR + nt * 16 + q * 4;
            d[0] = h0; d[1] = h1; d[2] = h2; d[3] = h3;
        }
    }

    // ---------------- head: leaky + dot(W_out) from final fp32 accs ----------------
    {
        float s = 0.f;
#pragma unroll
        for (int nt = 0; nt < NT; ++nt) {
            f32x4 w4 = *(const f32x4*)(woutp + nt * 16 + q * 4);
#pragma unroll
            for (int r = 0; r < 4; ++r) {
                float a = acc[nt][r];
                float v = fmaxf(a, 0.01f * a);
                s += v * w4[r];
            }
        }
        s += __shfl_xor(s, 16);   // reduce across the 4 q-groups
        s += __shfl_xor(s, 32);
        if (q == 0) {
            float aa = s + bout[0];
            float t = tanhf(aa);
            out[rowbase + l15] = t * 4.5f + 5.5f;   // (tanh+1)/2*9 + 1
        }
    }
}

extern "C" void kernel_launch(void* const* d_in, const int* in_sizes, int n_in,
                              void* d_out, int out_size, void* d_ws, size_t ws_size,
                              hipStream_t stream) {
    const float* x    = (const float*)d_in[0];
    const float* Win  = (const float*)d_in[1];
    const float* bin  = (const float*)d_in[2];
    const float* Ws   = (const float*)d_in[3];
    const float* bs   = (const float*)d_in[4];
    const float* Wout = (const float*)d_in[5];
    const float* bout = (const float*)d_in[6];
    float* out = (float*)d_out;

    char* ws = (char*)d_ws;
    _Float16* wsh  = (_Float16*)ws;
    _Float16* w0sh = wsh + WSH_HALVES;
    float* bpad  = (float*)(ws + OFF_BPAD_B);
    float* woutp = (float*)(ws + OFF_WOUT_B);

    hipLaunchKernelGGL(actor_prep, dim3((TOTAL_PREP + 255) / 256), dim3(256), 0, stream,
                       Win, bin, Ws, bs, Wout, wsh, w0sh, bpad, woutp);

    const int nrows = in_sizes[0] / DIN;   // 65536
    hipLaunchKernelGGL(actor_main, dim3(nrows / ROWS), dim3(64), 0, stream,
                       x, wsh, w0sh, bpad, woutp, bout, out);
}

// Round 10
// 286.883 us; speedup vs baseline: 1.7820x; 1.4810x over previous
//
#include <hip/hip_runtime.h>
#include <cmath>

// ---------------- problem constants ----------------
#define NLAYERS 100      // hidden layers (scan)
#define DIN     64       // input features
#define WDIM    100      // hidden width
#define NPAD    112      // padded N (7 tiles of 16)
#define NT      7        // n tiles
#define ROWS    32       // 2 independent 16-row blocks per wave, phase-shifted
#define PSTR    136      // f16 plane row stride (272 B: b128-aligned, pad cols 112..127)
#define PLANE   (16 * PSTR)   // one 16-row hi plane in halves (4352 B); 2 planes total

typedef _Float16 half8 __attribute__((ext_vector_type(8)));
typedef __fp16   fp16x2 __attribute__((ext_vector_type(2)));
typedef float    f32x4 __attribute__((ext_vector_type(4)));

// ---------------- workspace layout ----------------
#define WSH_LAYER_HALVES (NT * 4 * 64 * 8)               // 14336 halves per hidden layer
#define WSH_HALVES       (NLAYERS * WSH_LAYER_HALVES)    // 1,433,600
#define W0_HALVES        (NT * 2 * 64 * 8)               // 7168 (input layer, K=64)
#define BPAD_FLOATS      ((NLAYERS + 1) * NPAD)          // 11312 (row 0 = b_in acc init)
#define OFF_BPAD_B       ((WSH_HALVES + W0_HALVES) * 2)  // bytes, 16-aligned
#define OFF_WOUT_B       (OFF_BPAD_B + BPAD_FLOATS * 4)  // bytes, 16-aligned
#define TOTAL_PREP       (WSH_HALVES + W0_HALVES + BPAD_FLOATS + NPAD)

// ============================================================
// Prep: shuffle weights into MFMA A-operand order (f16), operand-swapped:
// frag (nt,ks), lane(q,l15), elem j holds W[k=ks*32+q*8+j][n=nt*16+l15].
// Row k==112 of each hidden-layer fragment = layer bias (h col 112 == 1.0).
// ============================================================
__global__ void actor_prep(const float* __restrict__ Win, const float* __restrict__ bin,
                           const float* __restrict__ Ws,  const float* __restrict__ bs,
                           const float* __restrict__ Wout,
                           _Float16* __restrict__ wsh, _Float16* __restrict__ w0sh,
                           float* __restrict__ bpad, float* __restrict__ woutp) {
    int t = blockIdx.x * 256 + threadIdx.x;
    if (t < WSH_HALVES) {                       // hidden-layer weights (+ bias row at k=112)
        int j    = t & 7;
        int lane = (t >> 3) & 63;
        int ks   = (t >> 9) & 3;
        int rest = t >> 11;                     // l*7 + nt
        int nt   = rest % 7;
        int l    = rest / 7;
        int qq = lane >> 4, ll = lane & 15;
        int k = ks * 32 + qq * 8 + j;
        int n = nt * 16 + ll;
        float v = 0.f;
        if (k < WDIM && n < WDIM)       v = Ws[(l * WDIM + k) * WDIM + n];
        else if (k == 112 && n < WDIM)  v = bs[l * WDIM + n];   // bias row
        wsh[t] = (_Float16)v;
        return;
    }
    int t2 = t - WSH_HALVES;
    if (t2 < W0_HALVES) {                       // input layer weights (K=64, bias via acc init)
        int j    = t2 & 7;
        int lane = (t2 >> 3) & 63;
        int ks   = (t2 >> 9) & 1;
        int nt   = t2 >> 10;
        int qq = lane >> 4, ll = lane & 15;
        int k = ks * 32 + qq * 8 + j;
        int n = nt * 16 + ll;
        float v = (k < DIN && n < WDIM) ? Win[k * WDIM + n] : 0.f;
        w0sh[t2] = (_Float16)v;
        return;
    }
    int t3 = t2 - W0_HALVES;
    if (t3 < BPAD_FLOATS) {                     // padded biases: row 0 = b_in
        int l = t3 / NPAD, c = t3 % NPAD;
        float v = 0.f;
        if (c < WDIM) v = (l == 0) ? bin[c] : bs[(l - 1) * WDIM + c];
        bpad[t3] = v;
        return;
    }
    int t4 = t3 - BPAD_FLOATS;
    if (t4 < NPAD) woutp[t4] = (t4 < WDIM) ? Wout[t4] : 0.f;
}

// split fp32 -> hi/lo fp16 (layer-0 input only: keep input fidelity)
__device__ __forceinline__ void split8(const float* __restrict__ p, half8& hi, half8& lo) {
    f32x4 u0 = *(const f32x4*)p;
    f32x4 u1 = *(const f32x4*)(p + 4);
    float v[8] = {u0[0], u0[1], u0[2], u0[3], u1[0], u1[1], u1[2], u1[3]};
#pragma unroll
    for (int e = 0; e < 8; e += 2) {
        fp16x2 h = __builtin_amdgcn_cvt_pkrtz(v[e], v[e + 1]);
        float r0 = v[e]     - (float)h[0];
        float r1 = v[e + 1] - (float)h[1];
        fp16x2 l = __builtin_amdgcn_cvt_pkrtz(r0, r1);
        hi[e] = (_Float16)h[0]; hi[e + 1] = (_Float16)h[1];
        lo[e] = (_Float16)l[0]; lo[e + 1] = (_Float16)l[1];
    }
}

// epilogue one C-tile: leaky + RNE f16 + contiguous 4-half store (ds_write_b64)
__device__ __forceinline__ void ep_tile(const f32x4 a, _Float16* __restrict__ d) {
    d[0] = (_Float16)fmaxf(a[0], 0.01f * a[0]);
    d[1] = (_Float16)fmaxf(a[1], 0.01f * a[1]);
    d[2] = (_Float16)fmaxf(a[2], 0.01f * a[2]);
    d[3] = (_Float16)fmaxf(a[3], 0.01f * a[3]);
}

// ============================================================
// Main: one wave/block, TWO independent 16-row blocks per wave executed
// HALF A LAYER OUT OF PHASE — breaks the phase-lock that pinned every
// prior config at ~10K cyc/layer (r3/r6/r8/r9 invariant):
//   Phase A: mfma0(L)  ||  epi1(L-1)   (independent: separate planes/accs)
//   Phase B: mfma1(L)  ||  epi0(L)  + prefetch W(L+1)
// MFMA and VALU/DS streams in each phase are data-independent, so the
// scheduler can co-issue them. Full layer W-frags register-resident
// (wb[4][7] = 112 VGPR), loaded ONCE per layer, used by both blocks.
// HI-ONLY f16 activations (absmax 0.094 verified r8/r9); bias rides W
// row k=112 vs h col 112 == 1.0. Heads from final fp32 accs in regs.
// No barriers. 2048 blocks = 2 waves/SIMD.
// ============================================================
__global__ __launch_bounds__(64, 2)
void actor_main(const float* __restrict__ x,
                const _Float16* __restrict__ wsh,
                const _Float16* __restrict__ w0sh,
                const float* __restrict__ bpad,
                const float* __restrict__ woutp,
                const float* __restrict__ bout,
                float* __restrict__ out) {
    __shared__ _Float16 hp[2 * PLANE];   // plane0 = block0, plane1 = block1
    const int lane = threadIdx.x;
    const int q = lane >> 4, l15 = lane & 15;
    const int rowbase = blockIdx.x * ROWS;

    f32x4 acc0[NT], acc1[NT];
    half8 wb[4][NT];                 // FULL layer of W fragments, register-resident
    const f32x4 zero4 = {0.f, 0.f, 0.f, 0.f};

    // ---- pad init: cols 112..127 zero in both planes, col 112 = 1.0 (bias mult) ----
    {
        if (lane < 32) {
            const int pl = lane >> 4, row = lane & 15;
            const half8 z = {0, 0, 0, 0, 0, 0, 0, 0};
            *(half8*)(hp + pl * PLANE + row * PSTR + 112) = z;
            *(half8*)(hp + pl * PLANE + row * PSTR + 120) = z;
            hp[pl * PLANE + row * PSTR + 112] = (_Float16)1.0f;
        }
    }

    // ---- input layer (K=64): load w0 frags once, mfma both blocks ----
#pragma unroll
    for (int ks = 0; ks < 2; ++ks)
#pragma unroll
        for (int nt = 0; nt < NT; ++nt)
            wb[ks][nt] = *(const half8*)(w0sh + ((nt * 2 + ks) * 64 + lane) * 8);
#pragma unroll
    for (int nt = 0; nt < NT; ++nt) {
        f32x4 b = *(const f32x4*)(bpad + nt * 16 + q * 4);
        acc0[nt] = b;
        acc1[nt] = b;
    }
#pragma unroll
    for (int ks = 0; ks < 2; ++ks) {           // block0 input mfma
        half8 xhi, xlo;
        split8(x + (rowbase + l15) * DIN + ks * 32 + q * 8, xhi, xlo);
#pragma unroll
        for (int nt = 0; nt < NT; ++nt) {
            acc0[nt] = __builtin_amdgcn_mfma_f32_16x16x32_f16(wb[ks][nt], xhi, acc0[nt], 0, 0, 0);
            acc0[nt] = __builtin_amdgcn_mfma_f32_16x16x32_f16(wb[ks][nt], xlo, acc0[nt], 0, 0, 0);
        }
    }
#pragma unroll
    for (int ks = 0; ks < 2; ++ks) {           // block1 input mfma
        half8 xhi, xlo;
        split8(x + (rowbase + 16 + l15) * DIN + ks * 32 + q * 8, xhi, xlo);
#pragma unroll
        for (int nt = 0; nt < NT; ++nt) {
            acc1[nt] = __builtin_amdgcn_mfma_f32_16x16x32_f16(wb[ks][nt], xhi, acc1[nt], 0, 0, 0);
            acc1[nt] = __builtin_amdgcn_mfma_f32_16x16x32_f16(wb[ks][nt], xlo, acc1[nt], 0, 0, 0);
        }
    }
    // prefetch W(0) into all 4 wb slots (latency covered by epi0 below)
#pragma unroll
    for (int ks = 0; ks < 4; ++ks)
#pragma unroll
        for (int nt = 0; nt < NT; ++nt)
            wb[ks][nt] = *(const half8*)(wsh + (ks * 64 + lane) * 8 + nt * 4 * 64 * 8);
    // epi0 -> hp plane0 (block1's epi deferred into layer-0 phase A)
#pragma unroll
    for (int nt = 0; nt < NT; ++nt)
        ep_tile(acc0[nt], hp + l15 * PSTR + nt * 16 + q * 4);

    // ---------------- 100 hidden layers, phase-split ----------------
    // invariant at loop top: hp0 = act(L-1) block0; acc1 = pre-act(L-1) block1
    //                        wb = W(L)
#pragma unroll 1
    for (int l = 0; l < NLAYERS; ++l) {
        const _Float16* wn = wsh + (l < NLAYERS - 1 ? l + 1 : l) * WSH_LAYER_HALVES;

        // ---- Phase A: mfma0(L) || epi1(L-1) ----
        {
            f32x4 p1[NT];                       // carry block1 pre-acts for epi
#pragma unroll
            for (int nt = 0; nt < NT; ++nt) { p1[nt] = acc1[nt]; acc0[nt] = zero4; }
            _Float16* d1 = hp + PLANE + l15 * PSTR + q * 4;
#pragma unroll
            for (int ks = 0; ks < 4; ++ks) {
                half8 b0 = *(const half8*)(hp + l15 * PSTR + ks * 32 + q * 8);
#pragma unroll
                for (int nt = 0; nt < NT; ++nt)
                    acc0[nt] = __builtin_amdgcn_mfma_f32_16x16x32_f16(wb[ks][nt], b0, acc0[nt], 0, 0, 0);
                // interleaved independent epi1 tiles (2,2,2,1)
                ep_tile(p1[2 * ks], d1 + (2 * ks) * 16);
                if (ks < 3) ep_tile(p1[2 * ks + 1], d1 + (2 * ks + 1) * 16);
            }
        }

        // ---- Phase B: mfma1(L) || epi0(L) + prefetch W(L+1) ----
        {
            f32x4 p0[NT];
#pragma unroll
            for (int nt = 0; nt < NT; ++nt) { p0[nt] = acc0[nt]; acc1[nt] = zero4; }
            _Float16* d0 = hp + l15 * PSTR + q * 4;
#pragma unroll
            for (int ks = 0; ks < 4; ++ks) {
                half8 b1 = *(const half8*)(hp + PLANE + l15 * PSTR + ks * 32 + q * 8);
#pragma unroll
                for (int nt = 0; nt < NT; ++nt)
                    acc1[nt] = __builtin_amdgcn_mfma_f32_16x16x32_f16(wb[ks][nt], b1, acc1[nt], 0, 0, 0);
                // wb[ks] now dead for this layer: refill with W(L+1)[ks]
#pragma unroll
                for (int nt = 0; nt < NT; ++nt)
                    wb[ks][nt] = *(const half8*)(wn + (ks * 64 + lane) * 8 + nt * 4 * 64 * 8);
                // interleaved independent epi0 tiles (2,2,2,1)
                ep_tile(p0[2 * ks], d0 + (2 * ks) * 16);
                if (ks < 3) ep_tile(p0[2 * ks + 1], d0 + (2 * ks + 1) * 16);
            }
            // restore acc0 = pre-act(L) for the final-layer head path
#pragma unroll
            for (int nt = 0; nt < NT; ++nt) acc0[nt] = p0[nt];
        }
    }
    // after loop: acc0 = pre(99) block0, acc1 = pre(99) block1 (both in regs)

    // ---------------- heads: leaky + dot(W_out) from fp32 accs ----------------
#pragma unroll
    for (int blk = 0; blk < 2; ++blk) {
        float s = 0.f;
#pragma unroll
        for (int nt = 0; nt < NT; ++nt) {
            f32x4 w4 = *(const f32x4*)(woutp + nt * 16 + q * 4);
            f32x4 a = blk ? acc1[nt] : acc0[nt];
#pragma unroll
            for (int r = 0; r < 4; ++r) {
                float v = fmaxf(a[r], 0.01f * a[r]);
                s += v * w4[r];
            }
        }
        s += __shfl_xor(s, 16);
        s += __shfl_xor(s, 32);
        if (q == 0) {
            float aa = s + bout[0];
            float t = tanhf(aa);
            out[rowbase + blk * 16 + l15] = t * 4.5f + 5.5f;   // (tanh+1)/2*9 + 1
        }
    }
}

extern "C" void kernel_launch(void* const* d_in, const int* in_sizes, int n_in,
                              void* d_out, int out_size, void* d_ws, size_t ws_size,
                              hipStream_t stream) {
    const float* x    = (const float*)d_in[0];
    const float* Win  = (const float*)d_in[1];
    const float* bin  = (const float*)d_in[2];
    const float* Ws   = (const float*)d_in[3];
    const float* bs   = (const float*)d_in[4];
    const float* Wout = (const float*)d_in[5];
    const float* bout = (const float*)d_in[6];
    float* out = (float*)d_out;

    char* ws = (char*)d_ws;
    _Float16* wsh  = (_Float16*)ws;
    _Float16* w0sh = wsh + WSH_HALVES;
    float* bpad  = (float*)(ws + OFF_BPAD_B);
    float* woutp = (float*)(ws + OFF_WOUT_B);

    hipLaunchKernelGGL(actor_prep, dim3((TOTAL_PREP + 255) / 256), dim3(256), 0, stream,
                       Win, bin, Ws, bs, Wout, wsh, w0sh, bpad, woutp);

    const int nrows = in_sizes[0] / DIN;   // 65536
    hipLaunchKernelGGL(actor_main, dim3(nrows / ROWS), dim3(64), 0, stream,
                       x, wsh, w0sh, bpad, woutp, bout, out);
}

// Round 11
// 271.751 us; speedup vs baseline: 1.8812x; 1.0557x over previous
//
#include <hip/hip_runtime.h>
#include <cmath>

// ---------------- problem constants ----------------
#define NLAYERS 100      // hidden layers (scan)
#define DIN     64       // input features
#define WDIM    100      // hidden width
#define NPAD    112      // padded N (7 tiles of 16)
#define NT      7        // n tiles
#define ROWS    32       // 2 independent 16-row blocks per wave, phase-shifted
#define PSTR    136      // f16 plane row stride (272 B: b128-aligned, pad cols 112..127)
#define PLANE   (16 * PSTR)   // one 16-row hi plane in halves (4352 B); 2 planes total

typedef _Float16 half8 __attribute__((ext_vector_type(8)));
typedef _Float16 half2v __attribute__((ext_vector_type(2)));
typedef __fp16   fp16x2 __attribute__((ext_vector_type(2)));
typedef float    f32x4 __attribute__((ext_vector_type(4)));

// ---------------- workspace layout ----------------
// wsh layout: [l][ks][nt][lane][8]  -- frag stride 512 halves (1024 B), so
// hidden-layer loads are s_base(+ks) + voffset(lane*16) + imm(nt*1024 B):
// zero per-load VALU address math (nt*1024 <= 3072 fits the 13-bit imm
// with a second base for nt>=4 if the compiler wants one).
#define WSH_LAYER_HALVES (4 * NT * 64 * 8)               // 14336 halves per hidden layer
#define WSH_HALVES       (NLAYERS * WSH_LAYER_HALVES)    // 1,433,600
#define W0_HALVES        (2 * NT * 64 * 8)               // 7168 (input layer, K=64)
#define BPAD_FLOATS      ((NLAYERS + 1) * NPAD)          // 11312 (row 0 = b_in acc init)
#define OFF_BPAD_B       ((WSH_HALVES + W0_HALVES) * 2)  // bytes, 16-aligned
#define OFF_WOUT_B       (OFF_BPAD_B + BPAD_FLOATS * 4)  // bytes, 16-aligned
#define TOTAL_PREP       (WSH_HALVES + W0_HALVES + BPAD_FLOATS + NPAD)

// ============================================================
// Prep: shuffle weights into MFMA A-operand order (f16), operand-swapped:
// within a frag, lane(q,l15), elem j holds W[k=ks*32+q*8+j][n=nt*16+l15].
// Frag storage order: [l][ks][nt] (nt innermost, 1024 B stride).
// Row k==112 of each hidden-layer fragment = layer bias (h col 112 == 1.0).
// ============================================================
__global__ void actor_prep(const float* __restrict__ Win, const float* __restrict__ bin,
                           const float* __restrict__ Ws,  const float* __restrict__ bs,
                           const float* __restrict__ Wout,
                           _Float16* __restrict__ wsh, _Float16* __restrict__ w0sh,
                           float* __restrict__ bpad, float* __restrict__ woutp) {
    int t = blockIdx.x * 256 + threadIdx.x;
    if (t < WSH_HALVES) {                       // hidden-layer weights (+ bias row at k=112)
        int j    = t & 7;
        int lane = (t >> 3) & 63;
        int fid  = t >> 9;                      // (l*4 + ks)*7 + nt
        int nt   = fid % 7;
        int r2   = fid / 7;
        int ks   = r2 & 3;
        int l    = r2 >> 2;
        int qq = lane >> 4, ll = lane & 15;
        int k = ks * 32 + qq * 8 + j;
        int n = nt * 16 + ll;
        float v = 0.f;
        if (k < WDIM && n < WDIM)       v = Ws[(l * WDIM + k) * WDIM + n];
        else if (k == 112 && n < WDIM)  v = bs[l * WDIM + n];   // bias row
        wsh[t] = (_Float16)v;
        return;
    }
    int t2 = t - WSH_HALVES;
    if (t2 < W0_HALVES) {                       // input layer weights, [ks][nt] frag order
        int j    = t2 & 7;
        int lane = (t2 >> 3) & 63;
        int fid  = t2 >> 9;                     // ks*7 + nt
        int nt   = fid % 7;
        int ks   = fid / 7;
        int qq = lane >> 4, ll = lane & 15;
        int k = ks * 32 + qq * 8 + j;
        int n = nt * 16 + ll;
        float v = (k < DIN && n < WDIM) ? Win[k * WDIM + n] : 0.f;
        w0sh[t2] = (_Float16)v;
        return;
    }
    int t3 = t2 - W0_HALVES;
    if (t3 < BPAD_FLOATS) {                     // padded biases: row 0 = b_in
        int l = t3 / NPAD, c = t3 % NPAD;
        float v = 0.f;
        if (c < WDIM) v = (l == 0) ? bin[c] : bs[(l - 1) * WDIM + c];
        bpad[t3] = v;
        return;
    }
    int t4 = t3 - BPAD_FLOATS;
    if (t4 < NPAD) woutp[t4] = (t4 < WDIM) ? Wout[t4] : 0.f;
}

// split fp32 -> hi/lo fp16 (layer-0 input only: keep input fidelity)
__device__ __forceinline__ void split8(const float* __restrict__ p, half8& hi, half8& lo) {
    f32x4 u0 = *(const f32x4*)p;
    f32x4 u1 = *(const f32x4*)(p + 4);
    float v[8] = {u0[0], u0[1], u0[2], u0[3], u1[0], u1[1], u1[2], u1[3]};
#pragma unroll
    for (int e = 0; e < 8; e += 2) {
        fp16x2 h = __builtin_amdgcn_cvt_pkrtz(v[e], v[e + 1]);
        float r0 = v[e]     - (float)h[0];
        float r1 = v[e + 1] - (float)h[1];
        fp16x2 l = __builtin_amdgcn_cvt_pkrtz(r0, r1);
        hi[e] = (_Float16)h[0]; hi[e + 1] = (_Float16)h[1];
        lo[e] = (_Float16)l[0]; lo[e + 1] = (_Float16)l[1];
    }
}

// epilogue one C-tile: RNE f16 cvt, then packed-f16 leaky (v_pk_mul+v_pk_max),
// single b64 store. Leaky-after-round differs from round-after-leaky by <=1
// f16 ulp on the 0.01-slope branch only — invisible vs the 0.094 error floor.
__device__ __forceinline__ void ep_tile(const f32x4 a, _Float16* __restrict__ d) {
    half2v p01, p23;
    p01[0] = (_Float16)a[0]; p01[1] = (_Float16)a[1];   // RNE casts
    p23[0] = (_Float16)a[2]; p23[1] = (_Float16)a[3];
    const half2v slope = {(_Float16)0.01f, (_Float16)0.01f};
    p01 = __builtin_elementwise_max(p01, p01 * slope);
    p23 = __builtin_elementwise_max(p23, p23 * slope);
    uint2 w;
    w.x = __builtin_bit_cast(unsigned, p01);
    w.y = __builtin_bit_cast(unsigned, p23);
    *reinterpret_cast<uint2*>(d) = w;                    // ds_write_b64
}

// ============================================================
// Main: one wave/block, TWO independent 16-row blocks per wave, executed
// HALF A LAYER OUT OF PHASE (r10 win: broke the ~10K cyc/layer phase-lock):
//   Phase A: mfma0(L)  ||  epi1(L-1)   — epi reads acc1 DIRECTLY (no copies)
//   Phase B: mfma1(L)  ||  epi0(L) + prefetch W(L+1)  — epi reads acc0 directly
// r11 changes: dead p0/p1/restore copies removed (-84 v_mov/layer/wave),
// frag-contiguous weight layout (imm-offset loads, no per-load VALU addr),
// packed-f16 epilogue. Full layer W-frags register-resident (wb[4][7]).
// HI-ONLY f16 activations (absmax 0.094 verified r8-r10); bias rides W row
// k=112 vs h col 112 == 1.0. Heads from final fp32 accs. No barriers.
// ============================================================
__global__ __launch_bounds__(64, 2)
void actor_main(const float* __restrict__ x,
                const _Float16* __restrict__ wsh,
                const _Float16* __restrict__ w0sh,
                const float* __restrict__ bpad,
                const float* __restrict__ woutp,
                const float* __restrict__ bout,
                float* __restrict__ out) {
    __shared__ _Float16 hp[2 * PLANE];   // plane0 = block0, plane1 = block1
    const int lane = threadIdx.x;
    const int q = lane >> 4, l15 = lane & 15;
    const int rowbase = blockIdx.x * ROWS;

    f32x4 acc0[NT], acc1[NT];
    half8 wb[4][NT];                 // FULL layer of W fragments, register-resident
    const f32x4 zero4 = {0.f, 0.f, 0.f, 0.f};

    // ---- pad init: cols 112..127 zero in both planes, col 112 = 1.0 (bias mult) ----
    {
        if (lane < 32) {
            const int pl = lane >> 4, row = lane & 15;
            const half8 z = {0, 0, 0, 0, 0, 0, 0, 0};
            *(half8*)(hp + pl * PLANE + row * PSTR + 112) = z;
            *(half8*)(hp + pl * PLANE + row * PSTR + 120) = z;
            hp[pl * PLANE + row * PSTR + 112] = (_Float16)1.0f;
        }
    }

    // ---- input layer (K=64): load w0 frags once, mfma both blocks ----
#pragma unroll
    for (int ks = 0; ks < 2; ++ks)
#pragma unroll
        for (int nt = 0; nt < NT; ++nt)
            wb[ks][nt] = *(const half8*)(w0sh + (ks * 7 + nt) * 512 + lane * 8);
#pragma unroll
    for (int nt = 0; nt < NT; ++nt) {
        f32x4 b = *(const f32x4*)(bpad + nt * 16 + q * 4);
        acc0[nt] = b;
        acc1[nt] = b;
    }
#pragma unroll
    for (int ks = 0; ks < 2; ++ks) {           // block0 input mfma
        half8 xhi, xlo;
        split8(x + (rowbase + l15) * DIN + ks * 32 + q * 8, xhi, xlo);
#pragma unroll
        for (int nt = 0; nt < NT; ++nt) {
            acc0[nt] = __builtin_amdgcn_mfma_f32_16x16x32_f16(wb[ks][nt], xhi, acc0[nt], 0, 0, 0);
            acc0[nt] = __builtin_amdgcn_mfma_f32_16x16x32_f16(wb[ks][nt], xlo, acc0[nt], 0, 0, 0);
        }
    }
#pragma unroll
    for (int ks = 0; ks < 2; ++ks) {           // block1 input mfma
        half8 xhi, xlo;
        split8(x + (rowbase + 16 + l15) * DIN + ks * 32 + q * 8, xhi, xlo);
#pragma unroll
        for (int nt = 0; nt < NT; ++nt) {
            acc1[nt] = __builtin_amdgcn_mfma_f32_16x16x32_f16(wb[ks][nt], xhi, acc1[nt], 0, 0, 0);
            acc1[nt] = __builtin_amdgcn_mfma_f32_16x16x32_f16(wb[ks][nt], xlo, acc1[nt], 0, 0, 0);
        }
    }
    // prefetch W(0) into all 4 wb slots (latency covered by epi0 below)
#pragma unroll
    for (int ks = 0; ks < 4; ++ks) {
        const _Float16* wk = wsh + (ks * 7) * 512;
#pragma unroll
        for (int nt = 0; nt < NT; ++nt)
            wb[ks][nt] = *(const half8*)(wk + nt * 512 + lane * 8);
    }
    // epi0 -> hp plane0 (block1's epi deferred into layer-0 phase A)
#pragma unroll
    for (int nt = 0; nt < NT; ++nt)
        ep_tile(acc0[nt], hp + l15 * PSTR + nt * 16 + q * 4);

    // ---------------- 100 hidden layers, phase-split ----------------
    // invariant at loop top: hp0 = act(L-1) block0; acc1 = pre-act(L-1) block1
    //                        wb = W(L)
#pragma unroll 1
    for (int l = 0; l < NLAYERS; ++l) {
        const _Float16* wn = wsh + (l < NLAYERS - 1 ? l + 1 : l) * WSH_LAYER_HALVES;

        // ---- Phase A: mfma0(L) || epi1(L-1) — epi reads acc1 directly ----
        {
#pragma unroll
            for (int nt = 0; nt < NT; ++nt) acc0[nt] = zero4;
            _Float16* d1 = hp + PLANE + l15 * PSTR + q * 4;
#pragma unroll
            for (int ks = 0; ks < 4; ++ks) {
                half8 b0 = *(const half8*)(hp + l15 * PSTR + ks * 32 + q * 8);
#pragma unroll
                for (int nt = 0; nt < NT; ++nt)
                    acc0[nt] = __builtin_amdgcn_mfma_f32_16x16x32_f16(wb[ks][nt], b0, acc0[nt], 0, 0, 0);
                // interleaved independent epi1 tiles (2,2,2,1): acc1 untouched by mfma here
                ep_tile(acc1[2 * ks], d1 + (2 * ks) * 16);
                if (ks < 3) ep_tile(acc1[2 * ks + 1], d1 + (2 * ks + 1) * 16);
            }
        }

        // ---- Phase B: mfma1(L) || epi0(L) + prefetch W(L+1) — epi reads acc0 directly ----
        {
#pragma unroll
            for (int nt = 0; nt < NT; ++nt) acc1[nt] = zero4;
            _Float16* d0 = hp + l15 * PSTR + q * 4;
#pragma unroll
            for (int ks = 0; ks < 4; ++ks) {
                half8 b1 = *(const half8*)(hp + PLANE + l15 * PSTR + ks * 32 + q * 8);
#pragma unroll
                for (int nt = 0; nt < NT; ++nt)
                    acc1[nt] = __builtin_amdgcn_mfma_f32_16x16x32_f16(wb[ks][nt], b1, acc1[nt], 0, 0, 0);
                // wb[ks] dead for this layer: refill with W(L+1)[ks] (imm-offset loads)
                const _Float16* wk = wn + (ks * 7) * 512;
#pragma unroll
                for (int nt = 0; nt < NT; ++nt)
                    wb[ks][nt] = *(const half8*)(wk + nt * 512 + lane * 8);
                // interleaved independent epi0 tiles (2,2,2,1): acc0 untouched by mfma here
                ep_tile(acc0[2 * ks], d0 + (2 * ks) * 16);
                if (ks < 3) ep_tile(acc0[2 * ks + 1], d0 + (2 * ks + 1) * 16);
            }
        }
        // acc0 still holds pre(L) for the head after the final iteration
    }
    // after loop: acc0 = pre(99) block0, acc1 = pre(99) block1 (both in regs)

    // ---------------- heads: leaky + dot(W_out) from fp32 accs ----------------
#pragma unroll
    for (int blk = 0; blk < 2; ++blk) {
        float s = 0.f;
#pragma unroll
        for (int nt = 0; nt < NT; ++nt) {
            f32x4 w4 = *(const f32x4*)(woutp + nt * 16 + q * 4);
            f32x4 a = blk ? acc1[nt] : acc0[nt];
#pragma unroll
            for (int r = 0; r < 4; ++r) {
                float v = fmaxf(a[r], 0.01f * a[r]);
                s += v * w4[r];
            }
        }
        s += __shfl_xor(s, 16);
        s += __shfl_xor(s, 32);
        if (q == 0) {
            float aa = s + bout[0];
            float t = tanhf(aa);
            out[rowbase + blk * 16 + l15] = t * 4.5f + 5.5f;   // (tanh+1)/2*9 + 1
        }
    }
}

extern "C" void kernel_launch(void* const* d_in, const int* in_sizes, int n_in,
                              void* d_out, int out_size, void* d_ws, size_t ws_size,
                              hipStream_t stream) {
    const float* x    = (const float*)d_in[0];
    const float* Win  = (const float*)d_in[1];
    const float* bin  = (const float*)d_in[2];
    const float* Ws   = (const float*)d_in[3];
    const float* bs   = (const float*)d_in[4];
    const float* Wout = (const float*)d_in[5];
    const float* bout = (const float*)d_in[6];
    float* out = (float*)d_out;

    char* ws = (char*)d_ws;
    _Float16* wsh  = (_Float16*)ws;
    _Float16* w0sh = wsh + WSH_HALVES;
    float* bpad  = (float*)(ws + OFF_BPAD_B);
    float* woutp = (float*)(ws + OFF_WOUT_B);

    hipLaunchKernelGGL(actor_prep, dim3((TOTAL_PREP + 255) / 256), dim3(256), 0, stream,
                       Win, bin, Ws, bs, Wout, wsh, w0sh, bpad, woutp);

    const int nrows = in_sizes[0] / DIN;   // 65536
    hipLaunchKernelGGL(actor_main, dim3(nrows / ROWS), dim3(64), 0, stream,
                       x, wsh, w0sh, bpad, woutp, bout, out);
}